// Round 4
// baseline (226.310 us; speedup 1.0000x reference)
//
#include <hip/hip_runtime.h>

#define T_N   131072
#define K_N   64
#define L_C   128
#define F_N   8
#define N_CH  (T_N / L_C)   /* 1024 chunks per direction */
#define WARM  96
#define EPS_F 1e-10f
#define OBS_MAX ((T_N - 1) * F_N)

#define LOG2E 1.4426950408889634f
#define NL2E  (-0.72134752044448170f)   /* -0.5*log2(e) */
#define LN2   0.6931471805599453f
#define LN2PI 1.8378770664093453f
/* warm-up-only emission pre-scale 2^16 (see round-2 notes: store phase must
   stay at RAW emission scale to reproduce the reference's EPS saturation). */
#define EMSC  16.0f

typedef float v2f __attribute__((ext_vector_type(2)));
typedef __attribute__((ext_vector_type(8))) short short8;   /* 8 bf16 */
typedef __attribute__((ext_vector_type(4))) float f32x4;

/* ---- DPP wave64 sum: VALU-only ---- */
template <int CTRL>
__device__ __forceinline__ float dpp_add(float x) {
  int y = __builtin_amdgcn_update_dpp(0, __float_as_int(x), CTRL, 0xF, 0xF, true);
  return x + __int_as_float(y);
}
__device__ __forceinline__ float wave_sum64(float x) {
  x = dpp_add<0x111>(x);
  x = dpp_add<0x112>(x);
  x = dpp_add<0x114>(x);
  x = dpp_add<0x118>(x);
  x = dpp_add<0x142>(x);
  x = dpp_add<0x143>(x);
  return __int_as_float(__builtin_amdgcn_readlane(__float_as_int(x), 63));
}

#define PKFMA(a, b, c) __builtin_elementwise_fma(a, b, c)

/* bf16 round-to-nearest-even, bit form (preload only) */
__device__ __forceinline__ unsigned short bf16rn(float x) {
  unsigned u = __float_as_uint(x);
  unsigned r = u + 0x7FFFu + ((u >> 16) & 1u);
  return (unsigned short)(r >> 16);
}
__device__ __forceinline__ float ubf(unsigned short b) {
  return __uint_as_float(((unsigned)b) << 16);
}

/* emission: exp2(cc + sum_f x*(x*civ + cmiv)); coeffs pre-scaled by -0.5*log2e */
__device__ __forceinline__ float em_pk(const float4& xa, const float4& xb,
                                       const v2f civ2[4], const v2f cmiv2[4],
                                       float cc) {
  v2f x0 = {xa.x, xa.y}, x1 = {xa.z, xa.w};
  v2f x2 = {xb.x, xb.y}, x3 = {xb.z, xb.w};
  v2f a0 = {cc, 0.f}, a1 = {0.f, 0.f};
  a0 = PKFMA(x0, PKFMA(x0, civ2[0], cmiv2[0]), a0);
  a1 = PKFMA(x1, PKFMA(x1, civ2[1], cmiv2[1]), a1);
  a0 = PKFMA(x2, PKFMA(x2, civ2[2], cmiv2[2]), a0);
  a1 = PKFMA(x3, PKFMA(x3, civ2[3], cmiv2[3]), a1);
  v2f s = a0 + a1;
  return __builtin_amdgcn_exp2f(s.x + s.y);
}

#define MFMA16(A, B, C) __builtin_amdgcn_mfma_f32_16x16x32_bf16((A), (B), (C), 0, 0, 0)

/* 64x64 matvec on the MFMA pipe (VALU was the round-3 bottleneck: issue-bound,
   VALUBusy 68% with time invariant under latency changes).
   y = M v, M preloaded as bf16 hi/lo A-fragments (error-compensated: hh+lh+hl,
   rel err ~2^-17 == f32-grade). v (f32, lane=state) -> bf16 hi/lo -> LDS
   (2x ds_write_b16) -> replicated-column B-fragments (4x ds_read_b128: all 16
   lanes of a k-group read the same 16B => B[k][n]=v[k] for every n; column
   mapping of B therefore irrelevant, only k=(lane>>4)*8+j matters).
   Per-wave LDS ops are FIFO-ordered, single wave per block => no barrier.
   D layout (HW-verified m89): col=lane&15 (redundant), row=(lane>>4)*4+reg.
   Extraction: sender lane s holds y[dst] for dst=[ (s>>4&3)->rowgrp ] via
   own-bit select acc[mt=(s&15)>>2][reg=s&3], receiver l pulls from
   s(l) = ((l&15)>>2)*16 + (l>>4)*4 + (l&3)  (checked: l=0,5,63 all map right). */
#define MATVEC(VV, MOUT)                                                      \
  {                                                                           \
    int pkh_, pkl_;                                                           \
    asm("v_cvt_pk_bf16_f32 %0, %1, %2" : "=v"(pkh_) : "v"(VV), "v"(0.f));     \
    float hif_ = __uint_as_float(((unsigned)pkh_) << 16);                     \
    float lof_ = (VV) - hif_;                                                 \
    asm("v_cvt_pk_bf16_f32 %0, %1, %2" : "=v"(pkl_) : "v"(lof_), "v"(0.f));   \
    vtab[lane]      = (unsigned short)pkh_;                                   \
    vtab[64 + lane] = (unsigned short)pkl_;                                   \
    const short8 Bh0_ = *(const short8*)(vtab      + 8 * g);                  \
    const short8 Bh1_ = *(const short8*)(vtab + 32 + 8 * g);                  \
    const short8 Bl0_ = *(const short8*)(vtab + 64 + 8 * g);                  \
    const short8 Bl1_ = *(const short8*)(vtab + 96 + 8 * g);                  \
    const f32x4 z4_ = {0.f, 0.f, 0.f, 0.f};                                   \
    f32x4 accv_[4];                                                           \
    _Pragma("unroll")                                                         \
    for (int mt_ = 0; mt_ < 4; ++mt_) {                                       \
      f32x4 aA_ = MFMA16(Ahi[mt_][0], Bh0_, z4_);                             \
      f32x4 aB_ = MFMA16(Ahi[mt_][1], Bh1_, z4_);                             \
      aA_ = MFMA16(Alo[mt_][0], Bh0_, aA_);                                   \
      aB_ = MFMA16(Alo[mt_][1], Bh1_, aB_);                                   \
      aA_ = MFMA16(Ahi[mt_][0], Bl0_, aA_);                                   \
      aB_ = MFMA16(Ahi[mt_][1], Bl1_, aB_);                                   \
      accv_[mt_] = aA_ + aB_;                                                 \
    }                                                                         \
    f32x4 sA_ = mtb0 ? accv_[1] : accv_[0];                                   \
    f32x4 sB_ = mtb0 ? accv_[3] : accv_[2];                                   \
    f32x4 sC_ = mtb1 ? sB_ : sA_;                                             \
    float w01_ = rb0 ? sC_.y : sC_.x;                                         \
    float w23_ = rb0 ? sC_.w : sC_.z;                                         \
    float ws_  = rb1 ? w23_ : w01_;                                           \
    MOUT = __int_as_float(                                                    \
        __builtin_amdgcn_ds_bpermute(bpx, __float_as_int(ws_)));              \
  }

extern "C" __global__ void __launch_bounds__(64, 2)
hdphmm_fb(const float* __restrict__ obs,
          const float* __restrict__ beta_logits,
          const float* __restrict__ pi_logits,
          const float* __restrict__ means,
          const float* __restrict__ log_vars,
          float* __restrict__ out) {
  const int lane = threadIdx.x;
  const int bid  = blockIdx.x;
  const int g    = lane >> 4;        /* k-group for A/B fragments */
  const int h16  = lane & 15;        /* row within M-tile for A    */
  const bool mtb0 = (lane >> 2) & 1; /* mt select bits = (lane&15)>>2 */
  const bool mtb1 = (lane >> 3) & 1;
  const bool rb0  = lane & 1;        /* reg select bits = lane&3 */
  const bool rb1  = (lane >> 1) & 1;
  const int bpx = (((((lane & 15) >> 2) << 4) | ((lane >> 4) << 2) | (lane & 3)) << 2);

  __shared__ __align__(8) float2 sstat[K_N];
  __shared__ float sb[K_N];
  __shared__ __align__(16) unsigned short vtab[128];  /* bf16 v: hi[64], lo[64] */

  float* alpha   = out;
  float* betaout = out + (size_t)T_N * K_N;

  /* ---- per-lane emission coefficients (lane == state), packed ---- */
  v2f civ2[4], cmiv2[4];
  float c0, cw;   /* c0: raw scale (store phase); cw: +2^16 (warm-up only) */
  {
    const float4* mp = reinterpret_cast<const float4*>(means + lane * F_N);
    const float4* lp = reinterpret_cast<const float4*>(log_vars + lane * F_N);
    float4 m0 = mp[0], m1 = mp[1];
    float4 l0 = lp[0], l1 = lp[1];
    float mu[8] = {m0.x, m0.y, m0.z, m0.w, m1.x, m1.y, m1.z, m1.w};
    float lv[8] = {l0.x, l0.y, l0.z, l0.w, l1.x, l1.y, l1.z, l1.w};
    float cst = F_N * LN2PI;
#pragma unroll
    for (int f = 0; f < 8; ++f) {
      float iv = __builtin_amdgcn_exp2f(-lv[f] * LOG2E);
      cst += lv[f] + mu[f] * mu[f] * iv;
      float cf  = NL2E * iv;
      civ2[f >> 1][f & 1]  = cf;
      cmiv2[f >> 1][f & 1] = -2.0f * mu[f] * cf;
    }
    c0 = NL2E * cst;
    cw = c0 + EMSC;
  }

  /* ---- softmax stats (max, 1/sum) of pi_logits row `lane` -> LDS ---- */
  {
    const float4* pr4 = reinterpret_cast<const float4*>(pi_logits + lane * K_N);
    float mx = -3.0e38f;
#pragma unroll
    for (int k = 0; k < 16; ++k) {
      float4 r = pr4[k];
      mx = fmaxf(mx, fmaxf(fmaxf(r.x, r.y), fmaxf(r.z, r.w)));
    }
    float s = 0.0f;
#pragma unroll
    for (int k = 0; k < 16; ++k) {
      float4 r = pr4[k];
      s += __builtin_amdgcn_exp2f((r.x - mx) * LOG2E);
      s += __builtin_amdgcn_exp2f((r.y - mx) * LOG2E);
      s += __builtin_amdgcn_exp2f((r.z - mx) * LOG2E);
      s += __builtin_amdgcn_exp2f((r.w - mx) * LOG2E);
    }
    sstat[lane] = make_float2(mx, __builtin_amdgcn_rcpf(s));
  }
  __syncthreads();

  /* ---- A fragments: M = T^T (fwd) or T (bwd), bf16 hi + lo split.
     A[mt][kk] elem j = M[mt*16 + h16][kk*32 + g*8 + j]. ---- */
  short8 Ahi[4][2], Alo[4][2];

  if (bid < N_CH) {
    /* ================= FORWARD chunk =================  y[c]=sum_k v[k]T[k][c] */
#pragma unroll
    for (int mt = 0; mt < 4; ++mt)
#pragma unroll
      for (int kk = 0; kk < 2; ++kk) {
        int row = mt * 16 + h16;
        int kb  = kk * 32 + g * 8;
#pragma unroll
        for (int j = 0; j < 8; ++j) {
          int k = kb + j;
          float2 st = sstat[k];
          float tv = __builtin_amdgcn_exp2f(
                         (pi_logits[(size_t)k * K_N + row] - st.x) * LOG2E) * st.y;
          unsigned short hb = bf16rn(tv);
          unsigned short lb = bf16rn(tv - ubf(hb));
          Ahi[mt][kk][j] = (short)hb;
          Alo[mt][kk][j] = (short)lb;
        }
      }

    const int out_lo = bid * L_C;
    float v;
    int t_first;
    if (bid == 0) {
      /* exact stick-breaking init at RAW scale (reference EPS semantics) */
      float bl = beta_logits[lane];
      float ex = __builtin_amdgcn_exp2f(-bl * LOG2E);
      float bw = __builtin_amdgcn_rcpf(1.0f + ex);
      sb[lane] = 1.0f - bw;
      __syncthreads();
      float pr = 1.0f;
#pragma unroll
      for (int i = 0; i < 64; ++i) {
        float qv = sb[i];
        pr = (i < lane) ? pr * qv : pr;
      }
      float4 x0 = reinterpret_cast<const float4*>(obs)[0];
      float4 x1 = reinterpret_cast<const float4*>(obs)[1];
      v = bw * pr * em_pk(x0, x1, civ2, cmiv2, c0);
      t_first = 1;
    } else {
      const int t0 = out_lo - WARM;
      const float4* xp = reinterpret_cast<const float4*>(obs + t0 * F_N);
      v = em_pk(xp[0], xp[1], civ2, cmiv2, cw);   /* flat warm start, scaled */
      t_first = t0 + 1;
    }
    int obs_off = t_first * F_N;
    float4 xa, xb;
    {
      const float4* xp = reinterpret_cast<const float4*>(obs + obs_off);
      xa = xp[0]; xb = xp[1];
    }
    int out_off = out_lo * K_N + lane;

    /* ---- warm-up: scale-free recursion (scaled em), rescale every 8 ---- */
    const int wn8 = (bid == 0) ? 0 : (WARM >> 3);
#pragma unroll 1
    for (int o = 0; o < wn8; ++o) {
#pragma unroll
      for (int i = 0; i < 8; ++i) {
        float4 nxa = *reinterpret_cast<const float4*>(obs + obs_off + F_N);
        float4 nxb = *reinterpret_cast<const float4*>(obs + obs_off + F_N + 4);
        float m;
        MATVEC(v, m)
        float e = em_pk(xa, xb, civ2, cmiv2, cw);
        v = m * e;
        xa = nxa; xb = nxb; obs_off += F_N;
      }
      float Sw = wave_sum64(v);
      v *= __builtin_amdgcn_rcpf(Sw);
    }

    /* ---- store phase: RAW-scale em, reference EPS semantics ---- */
    float S = wave_sum64(v);
    float r_st = __builtin_amdgcn_rcpf(S + EPS_F);

#define FWD_SSTEP                                                             \
  {                                                                           \
    int offn = obs_off + F_N; offn = (offn > OBS_MAX) ? OBS_MAX : offn;       \
    float4 nxa = *reinterpret_cast<const float4*>(obs + offn);                \
    float4 nxb = *reinterpret_cast<const float4*>(obs + offn + 4);            \
    float m;                                                                  \
    MATVEC(v, m)                                                              \
    alpha[out_off] = v * r_st; out_off += K_N;                                \
    float e = em_pk(xa, xb, civ2, cmiv2, c0);                                 \
    float vn = m * (r_st * e);                                                \
    S = wave_sum64(vn);                                                       \
    r_st = __builtin_amdgcn_rcpf(S + EPS_F);                                  \
    v = vn; xa = nxa; xb = nxb; obs_off = offn;                               \
  }

#pragma unroll 2
    for (int it = 0; it < L_C - 1; ++it) FWD_SSTEP
#undef FWD_SSTEP
    alpha[out_off] = v * r_st;
    if (bid == N_CH - 1 && lane == 0) {
      float sl = S * r_st + EPS_F;
      out[(size_t)2 * T_N * K_N] = __builtin_amdgcn_logf(sl) * LN2;
    }
  } else {
    /* ================= BACKWARD chunk =================  y[i]=sum_k T[i][k]w[k] */
#pragma unroll
    for (int mt = 0; mt < 4; ++mt) {
      int row = mt * 16 + h16;
      float2 st = sstat[row];
#pragma unroll
      for (int kk = 0; kk < 2; ++kk) {
        int kb = kk * 32 + g * 8;
#pragma unroll
        for (int j = 0; j < 8; ++j) {
          int k = kb + j;
          float tv = __builtin_amdgcn_exp2f(
                         (pi_logits[(size_t)row * K_N + k] - st.x) * LOG2E) * st.y;
          unsigned short hb = bf16rn(tv);
          unsigned short lb = bf16rn(tv - ubf(hb));
          Ahi[mt][kk][j] = (short)hb;
          Alo[mt][kk][j] = (short)lb;
        }
      }
    }

    const int cb   = bid - N_CH;
    const int t_lo = cb * L_C;
    const int t_hi = t_lo + L_C - 1;
    int t_top = t_hi + WARM;
    if (t_top > T_N - 1) t_top = T_N - 1;        /* clamp => exact bT anchor */
    const int s_top = (cb == N_CH - 1) ? T_N - 2 : t_hi;

    float w;
    {
      const float4* xp = reinterpret_cast<const float4*>(obs + t_top * F_N);
      w = em_pk(xp[0], xp[1], civ2, cmiv2, cw);   /* scale divided out later */
    }
    if (cb == N_CH - 1)
      betaout[(size_t)(T_N - 1) * K_N + lane] = 1.0f;
    int obs_off = (t_top - 1) * F_N;
    float4 xa, xb;
    {
      const float4* xp = reinterpret_cast<const float4*>(obs + obs_off);
      xa = xp[0]; xb = xp[1];
    }
    int out_off = s_top * K_N + lane;

    /* ---- warm-up (scale-free, scaled em), pw = warm_n - 1 steps ---- */
#define BWD_WSTEP                                                             \
  {                                                                           \
    float4 nxa = *reinterpret_cast<const float4*>(obs + obs_off - F_N);       \
    float4 nxb = *reinterpret_cast<const float4*>(obs + obs_off - F_N + 4);   \
    float m;                                                                  \
    MATVEC(w, m)                                                              \
    float e = em_pk(xa, xb, civ2, cmiv2, cw);                                 \
    w = m * e;                                                                \
    xa = nxa; xb = nxb; obs_off -= F_N;                                       \
  }

    const int pw  = (t_top - s_top) - 1;         /* 95 generic, 0 last chunk */
    const int pw8 = pw >> 3, pwr = pw & 7;
#pragma unroll 1
    for (int o = 0; o < pw8; ++o) {
#pragma unroll
      for (int i = 0; i < 8; ++i) BWD_WSTEP
      float Sw = wave_sum64(w);
      w *= __builtin_amdgcn_rcpf(Sw);
    }
#pragma unroll 1
    for (int it = 0; it < pwr; ++it) BWD_WSTEP
#undef BWD_WSTEP

    /* ---- transition: exact direction normalize, switch to RAW-scale em ---- */
    float u, S, r_st;
    {
      float m;
      MATVEC(w, m)
      float Sm = wave_sum64(m);
      u = m * __builtin_amdgcn_rcpf(Sm);          /* b(s_top), sum == 1 */
      float e = em_pk(xa, xb, civ2, cmiv2, c0);   /* em[s_top], raw scale */
      w = u * e;
      S = wave_sum64(u);
      r_st = __builtin_amdgcn_rcpf(S + EPS_F);
      int offn = obs_off - F_N; offn = (offn < 0) ? 0 : offn;
      xa = *reinterpret_cast<const float4*>(obs + offn);
      xb = *reinterpret_cast<const float4*>(obs + offn + 4);
      obs_off = offn;
    }

#define BWD_SSTEP                                                             \
  {                                                                           \
    int offn = obs_off - F_N; offn = (offn < 0) ? 0 : offn;                   \
    float4 nxa = *reinterpret_cast<const float4*>(obs + offn);                \
    float4 nxb = *reinterpret_cast<const float4*>(obs + offn + 4);            \
    float m;                                                                  \
    MATVEC(w, m)                                                              \
    betaout[out_off] = u * r_st; out_off -= K_N;                              \
    float u2 = m * r_st;                                                      \
    float e = em_pk(xa, xb, civ2, cmiv2, c0);                                 \
    w = u2 * e;                                                               \
    S = wave_sum64(u2);                                                       \
    r_st = __builtin_amdgcn_rcpf(S + EPS_F);                                  \
    u = u2; xa = nxa; xb = nxb; obs_off = offn;                               \
  }

    const int store_n = s_top - t_lo;
#pragma unroll 2
    for (int it = 0; it < store_n; ++it) BWD_SSTEP
#undef BWD_SSTEP
    betaout[t_lo * K_N + lane] = u * r_st;
  }
}

extern "C" void kernel_launch(void* const* d_in, const int* in_sizes, int n_in,
                              void* d_out, int out_size, void* d_ws, size_t ws_size,
                              hipStream_t stream) {
  (void)in_sizes; (void)n_in; (void)out_size; (void)d_ws; (void)ws_size;
  const float* obs  = (const float*)d_in[0];
  const float* bl   = (const float*)d_in[1];
  const float* pi   = (const float*)d_in[2];
  const float* mns  = (const float*)d_in[3];
  const float* lvs  = (const float*)d_in[4];
  hipLaunchKernelGGL(hdphmm_fb, dim3(2 * N_CH), dim3(64), 0, stream,
                     obs, bl, pi, mns, lvs, (float*)d_out);
}

// Round 6
// 172.299 us; speedup vs baseline: 1.3135x; 1.3135x over previous
//
#include <hip/hip_runtime.h>

#define T_N   131072
#define K_N   64
#define L_C   128
#define F_N   8
#define N_CH  (T_N / L_C)   /* 1024 chunks per direction */
#define WARM  96
#define EPS_F 1e-10f
#define OBS_MAX ((T_N - 1) * F_N)

#define LOG2E 1.4426950408889634f
#define NL2E  (-0.72134752044448170f)   /* -0.5*log2(e) */
#define LN2   0.6931471805599453f
#define LN2PI 1.8378770664093453f
/* warm-up-only emission pre-scale 2^16 (round-2 lesson: store phase must
   stay at RAW emission scale to reproduce the reference's EPS saturation). */
#define EMSC  16.0f

typedef float v2f __attribute__((ext_vector_type(2)));
typedef __attribute__((ext_vector_type(4))) float f32x4;

/* ---- DPP wave64 sum: VALU-only ---- */
template <int CTRL>
__device__ __forceinline__ float dpp_add(float x) {
  int y = __builtin_amdgcn_update_dpp(0, __float_as_int(x), CTRL, 0xF, 0xF, true);
  return x + __int_as_float(y);
}
__device__ __forceinline__ float wave_sum64(float x) {
  x = dpp_add<0x111>(x);
  x = dpp_add<0x112>(x);
  x = dpp_add<0x114>(x);
  x = dpp_add<0x118>(x);
  x = dpp_add<0x142>(x);
  x = dpp_add<0x143>(x);
  return __int_as_float(__builtin_amdgcn_readlane(__float_as_int(x), 63));
}

#define PKFMA(a, b, c) __builtin_elementwise_fma(a, b, c)

/* emission: exp2(cc + sum_f x*(x*civ + cmiv)); coeffs pre-scaled by -0.5*log2e */
__device__ __forceinline__ float em_pk(const float4& xa, const float4& xb,
                                       const v2f civ2[4], const v2f cmiv2[4],
                                       float cc) {
  v2f x0 = {xa.x, xa.y}, x1 = {xa.z, xa.w};
  v2f x2 = {xb.x, xb.y}, x3 = {xb.z, xb.w};
  v2f a0 = {cc, 0.f}, a1 = {0.f, 0.f};
  a0 = PKFMA(x0, PKFMA(x0, civ2[0], cmiv2[0]), a0);
  a1 = PKFMA(x1, PKFMA(x1, civ2[1], cmiv2[1]), a1);
  a0 = PKFMA(x2, PKFMA(x2, civ2[2], cmiv2[2]), a0);
  a1 = PKFMA(x3, PKFMA(x3, civ2[3], cmiv2[3]), a1);
  v2f s = a0 + a1;
  return __builtin_amdgcn_exp2f(s.x + s.y);
}

/* 64x64 matvec via LDS broadcast (round-4 MFMA port regressed: matvec is
   latency-bound and MFMA dependent-use latency >> VALU; round-3 VALU path is
   issue-bound, so this version removes its data-movement VALU ops instead).
   Each lane owns ROW `lane` of M (f32 v2f[32], 64 VGPR). Per step: lane
   writes its scalar state to vtab (ds_write_b32, 2-way bank alias = free),
   reads back all 64 states as 16 broadcast ds_read_b128 (same-addr across
   lanes: conflict-free, DS pipe), and runs 32 pk_fma. The 15-op DPP gather +
   16 splats + 8 permlane swaps + 8 adds + 3 selects of round 3 (~70 cyc of
   VALU per step) are gone. In-wave DS write->read needs no barrier (single
   wave; DS pipe is in-order per wave -- validated by round 4's pass). */
#define MATVEC(VV, MOUT)                                                      \
  {                                                                           \
    vtab[lane] = (VV);                                                        \
    v2f ac0_ = {0.f, 0.f}, ac1_ = {0.f, 0.f};                                 \
    v2f ac2_ = {0.f, 0.f}, ac3_ = {0.f, 0.f};                                 \
    _Pragma("unroll")                                                         \
    for (int r_ = 0; r_ < 16; ++r_) {                                         \
      f32x4 q_ = ((const f32x4*)vtab)[r_];                                    \
      v2f lo_ = __builtin_shufflevector(q_, q_, 0, 1);                        \
      v2f hi_ = __builtin_shufflevector(q_, q_, 2, 3);                        \
      if (r_ & 1) {                                                           \
        ac2_ = PKFMA(lo_, Tc[2 * r_],     ac2_);                              \
        ac3_ = PKFMA(hi_, Tc[2 * r_ + 1], ac3_);                              \
      } else {                                                                \
        ac0_ = PKFMA(lo_, Tc[2 * r_],     ac0_);                              \
        ac1_ = PKFMA(hi_, Tc[2 * r_ + 1], ac1_);                              \
      }                                                                       \
    }                                                                         \
    v2f s0_ = ac0_ + ac1_, s1_ = ac2_ + ac3_;                                 \
    v2f s2_ = s0_ + s1_;                                                      \
    MOUT = s2_.x + s2_.y;                                                     \
  }

extern "C" __global__ void __launch_bounds__(64, 2)
hdphmm_fb(const float* __restrict__ obs,
          const float* __restrict__ beta_logits,
          const float* __restrict__ pi_logits,
          const float* __restrict__ means,
          const float* __restrict__ log_vars,
          float* __restrict__ out) {
  const int lane = threadIdx.x;
  const int bid  = blockIdx.x;

  __shared__ __align__(8) float2 sstat[K_N];
  __shared__ float sb[K_N];
  __shared__ __align__(16) float vtab[K_N];   /* state broadcast table */

  float* alpha   = out;
  float* betaout = out + (size_t)T_N * K_N;

  /* ---- per-lane emission coefficients (lane == state), packed ---- */
  v2f civ2[4], cmiv2[4];
  float c0, cw;   /* c0: raw scale (store phase); cw: +2^16 (warm-up only) */
  {
    const float4* mp = reinterpret_cast<const float4*>(means + lane * F_N);
    const float4* lp = reinterpret_cast<const float4*>(log_vars + lane * F_N);
    float4 m0 = mp[0], m1 = mp[1];
    float4 l0 = lp[0], l1 = lp[1];
    float mu[8] = {m0.x, m0.y, m0.z, m0.w, m1.x, m1.y, m1.z, m1.w};
    float lv[8] = {l0.x, l0.y, l0.z, l0.w, l1.x, l1.y, l1.z, l1.w};
    float cst = F_N * LN2PI;
#pragma unroll
    for (int f = 0; f < 8; ++f) {
      float iv = __builtin_amdgcn_exp2f(-lv[f] * LOG2E);
      cst += lv[f] + mu[f] * mu[f] * iv;
      float cf  = NL2E * iv;
      civ2[f >> 1][f & 1]  = cf;
      cmiv2[f >> 1][f & 1] = -2.0f * mu[f] * cf;
    }
    c0 = NL2E * cst;
    cw = c0 + EMSC;
  }

  /* ---- softmax stats (max, 1/sum) of pi_logits row `lane` -> LDS ---- */
  {
    const float4* pr4 = reinterpret_cast<const float4*>(pi_logits + lane * K_N);
    float mx = -3.0e38f;
#pragma unroll
    for (int k = 0; k < 16; ++k) {
      float4 r = pr4[k];
      mx = fmaxf(mx, fmaxf(fmaxf(r.x, r.y), fmaxf(r.z, r.w)));
    }
    float s = 0.0f;
#pragma unroll
    for (int k = 0; k < 16; ++k) {
      float4 r = pr4[k];
      s += __builtin_amdgcn_exp2f((r.x - mx) * LOG2E);
      s += __builtin_amdgcn_exp2f((r.y - mx) * LOG2E);
      s += __builtin_amdgcn_exp2f((r.z - mx) * LOG2E);
      s += __builtin_amdgcn_exp2f((r.w - mx) * LOG2E);
    }
    sstat[lane] = make_float2(mx, __builtin_amdgcn_rcpf(s));
  }
  __syncthreads();

  /* ---- per-lane M-row: Tc[j] = {M[lane][2j], M[lane][2j+1]} ---- */
  v2f Tc[32];

  if (bid < N_CH) {
    /* ================= FORWARD chunk =================
       y[c] = sum_k v[k]*trans[k][c]  =>  M = trans^T:
       M[lane][k] = trans[k][lane]  (column reads, per-k stats; one-time,
       pi_logits is 16 KB == L2-resident, preamble-only cost). */
#pragma unroll
    for (int j = 0; j < 32; ++j) {
      float2 sa = sstat[2 * j];
      float2 sbv = sstat[2 * j + 1];
      float p0 = pi_logits[(size_t)(2 * j) * K_N + lane];
      float p1 = pi_logits[(size_t)(2 * j + 1) * K_N + lane];
      Tc[j] = (v2f){__builtin_amdgcn_exp2f((p0 - sa.x) * LOG2E) * sa.y,
                    __builtin_amdgcn_exp2f((p1 - sbv.x) * LOG2E) * sbv.y};
    }

    const int out_lo = bid * L_C;
    float v;
    int t_first;
    if (bid == 0) {
      /* exact stick-breaking init at RAW scale (reference EPS semantics) */
      float bl = beta_logits[lane];
      float ex = __builtin_amdgcn_exp2f(-bl * LOG2E);
      float bw = __builtin_amdgcn_rcpf(1.0f + ex);
      sb[lane] = 1.0f - bw;
      __syncthreads();
      float pr = 1.0f;
#pragma unroll
      for (int i = 0; i < 64; ++i) {
        float qv = sb[i];
        pr = (i < lane) ? pr * qv : pr;
      }
      float4 x0 = reinterpret_cast<const float4*>(obs)[0];
      float4 x1 = reinterpret_cast<const float4*>(obs)[1];
      v = bw * pr * em_pk(x0, x1, civ2, cmiv2, c0);
      t_first = 1;
    } else {
      const int t0 = out_lo - WARM;
      const float4* xp = reinterpret_cast<const float4*>(obs + t0 * F_N);
      v = em_pk(xp[0], xp[1], civ2, cmiv2, cw);   /* flat warm start, scaled */
      t_first = t0 + 1;
    }
    int obs_off = t_first * F_N;
    float4 xa, xb;
    {
      const float4* xp = reinterpret_cast<const float4*>(obs + obs_off);
      xa = xp[0]; xb = xp[1];
    }
    int out_off = out_lo * K_N + lane;

    /* ---- warm-up: scale-free recursion (scaled em), rescale every 8 ---- */
    const int wn8 = (bid == 0) ? 0 : (WARM >> 3);
#pragma unroll 1
    for (int o = 0; o < wn8; ++o) {
#pragma unroll
      for (int i = 0; i < 8; ++i) {
        float4 nxa = *reinterpret_cast<const float4*>(obs + obs_off + F_N);
        float4 nxb = *reinterpret_cast<const float4*>(obs + obs_off + F_N + 4);
        float m;
        MATVEC(v, m)
        float e = em_pk(xa, xb, civ2, cmiv2, cw);
        v = m * e;
        xa = nxa; xb = nxb; obs_off += F_N;
      }
      float Sw = wave_sum64(v);
      v *= __builtin_amdgcn_rcpf(Sw);
    }

    /* ---- store phase: RAW-scale em, reference EPS semantics ---- */
    float S = wave_sum64(v);
    float r_st = __builtin_amdgcn_rcpf(S + EPS_F);

#define FWD_SSTEP                                                             \
  {                                                                           \
    int offn = obs_off + F_N; offn = (offn > OBS_MAX) ? OBS_MAX : offn;       \
    float4 nxa = *reinterpret_cast<const float4*>(obs + offn);                \
    float4 nxb = *reinterpret_cast<const float4*>(obs + offn + 4);            \
    float m;                                                                  \
    MATVEC(v, m)                                                              \
    alpha[out_off] = v * r_st; out_off += K_N;                                \
    float e = em_pk(xa, xb, civ2, cmiv2, c0);                                 \
    float vn = m * (r_st * e);                                                \
    S = wave_sum64(vn);                                                       \
    r_st = __builtin_amdgcn_rcpf(S + EPS_F);                                  \
    v = vn; xa = nxa; xb = nxb; obs_off = offn;                               \
  }

#pragma unroll 2
    for (int it = 0; it < L_C - 1; ++it) FWD_SSTEP
#undef FWD_SSTEP
    alpha[out_off] = v * r_st;
    if (bid == N_CH - 1 && lane == 0) {
      float sl = S * r_st + EPS_F;
      out[(size_t)2 * T_N * K_N] = __builtin_amdgcn_logf(sl) * LN2;
    }
  } else {
    /* ================= BACKWARD chunk =================
       y[i] = sum_k trans[i][k]*w[k]  =>  M = trans:
       M[lane][k] = trans[lane][k]  (own row, own stats, coalesced float4). */
    {
      float2 st = sstat[lane];
      const float4* pr4 = reinterpret_cast<const float4*>(pi_logits + lane * K_N);
#pragma unroll
      for (int j2 = 0; j2 < 16; ++j2) {
        float4 r = pr4[j2];
        Tc[2 * j2] = (v2f){__builtin_amdgcn_exp2f((r.x - st.x) * LOG2E) * st.y,
                           __builtin_amdgcn_exp2f((r.y - st.x) * LOG2E) * st.y};
        Tc[2 * j2 + 1] =
            (v2f){__builtin_amdgcn_exp2f((r.z - st.x) * LOG2E) * st.y,
                  __builtin_amdgcn_exp2f((r.w - st.x) * LOG2E) * st.y};
      }
    }

    const int cb   = bid - N_CH;
    const int t_lo = cb * L_C;
    const int t_hi = t_lo + L_C - 1;
    int t_top = t_hi + WARM;
    if (t_top > T_N - 1) t_top = T_N - 1;        /* clamp => exact bT anchor */
    const int s_top = (cb == N_CH - 1) ? T_N - 2 : t_hi;

    float w;
    {
      const float4* xp = reinterpret_cast<const float4*>(obs + t_top * F_N);
      w = em_pk(xp[0], xp[1], civ2, cmiv2, cw);   /* scale divided out later */
    }
    if (cb == N_CH - 1)
      betaout[(size_t)(T_N - 1) * K_N + lane] = 1.0f;
    int obs_off = (t_top - 1) * F_N;
    float4 xa, xb;
    {
      const float4* xp = reinterpret_cast<const float4*>(obs + obs_off);
      xa = xp[0]; xb = xp[1];
    }
    int out_off = s_top * K_N + lane;

    /* ---- warm-up (scale-free, scaled em), pw = warm_n - 1 steps ---- */
#define BWD_WSTEP                                                             \
  {                                                                           \
    float4 nxa = *reinterpret_cast<const float4*>(obs + obs_off - F_N);       \
    float4 nxb = *reinterpret_cast<const float4*>(obs + obs_off - F_N + 4);   \
    float m;                                                                  \
    MATVEC(w, m)                                                              \
    float e = em_pk(xa, xb, civ2, cmiv2, cw);                                 \
    w = m * e;                                                                \
    xa = nxa; xb = nxb; obs_off -= F_N;                                       \
  }

    const int pw  = (t_top - s_top) - 1;         /* 95 generic, 0 last chunk */
    const int pw8 = pw >> 3, pwr = pw & 7;
#pragma unroll 1
    for (int o = 0; o < pw8; ++o) {
#pragma unroll
      for (int i = 0; i < 8; ++i) BWD_WSTEP
      float Sw = wave_sum64(w);
      w *= __builtin_amdgcn_rcpf(Sw);
    }
#pragma unroll 1
    for (int it = 0; it < pwr; ++it) BWD_WSTEP
#undef BWD_WSTEP

    /* ---- transition: exact direction normalize, switch to RAW-scale em ---- */
    float u, S, r_st;
    {
      float m;
      MATVEC(w, m)
      float Sm = wave_sum64(m);
      u = m * __builtin_amdgcn_rcpf(Sm);          /* b(s_top), sum == 1 */
      float e = em_pk(xa, xb, civ2, cmiv2, c0);   /* em[s_top], raw scale */
      w = u * e;
      S = wave_sum64(u);
      r_st = __builtin_amdgcn_rcpf(S + EPS_F);
      int offn = obs_off - F_N; offn = (offn < 0) ? 0 : offn;
      xa = *reinterpret_cast<const float4*>(obs + offn);
      xb = *reinterpret_cast<const float4*>(obs + offn + 4);
      obs_off = offn;
    }

#define BWD_SSTEP                                                             \
  {                                                                           \
    int offn = obs_off - F_N; offn = (offn < 0) ? 0 : offn;                   \
    float4 nxa = *reinterpret_cast<const float4*>(obs + offn);                \
    float4 nxb = *reinterpret_cast<const float4*>(obs + offn + 4);            \
    float m;                                                                  \
    MATVEC(w, m)                                                              \
    betaout[out_off] = u * r_st; out_off -= K_N;                              \
    float u2 = m * r_st;                                                      \
    float e = em_pk(xa, xb, civ2, cmiv2, c0);                                 \
    w = u2 * e;                                                               \
    S = wave_sum64(u2);                                                       \
    r_st = __builtin_amdgcn_rcpf(S + EPS_F);                                  \
    u = u2; xa = nxa; xb = nxb; obs_off = offn;                               \
  }

    const int store_n = s_top - t_lo;
#pragma unroll 2
    for (int it = 0; it < store_n; ++it) BWD_SSTEP
#undef BWD_SSTEP
    betaout[t_lo * K_N + lane] = u * r_st;
  }
}

extern "C" void kernel_launch(void* const* d_in, const int* in_sizes, int n_in,
                              void* d_out, int out_size, void* d_ws, size_t ws_size,
                              hipStream_t stream) {
  (void)in_sizes; (void)n_in; (void)out_size; (void)d_ws; (void)ws_size;
  const float* obs  = (const float*)d_in[0];
  const float* bl   = (const float*)d_in[1];
  const float* pi   = (const float*)d_in[2];
  const float* mns  = (const float*)d_in[3];
  const float* lvs  = (const float*)d_in[4];
  hipLaunchKernelGGL(hdphmm_fb, dim3(2 * N_CH), dim3(64), 0, stream,
                     obs, bl, pi, mns, lvs, (float*)d_out);
}

// Round 7
// 164.416 us; speedup vs baseline: 1.3764x; 1.0479x over previous
//
#include <hip/hip_runtime.h>

#define T_N   131072
#define K_N   64
#define L_C   128
#define F_N   8
#define N_CH  (T_N / L_C)   /* 1024 chunks per direction */
#define WARM  96
#define EPS_F 1e-10f
#define OBS_MAX ((T_N - 1) * F_N)

#define LOG2E 1.4426950408889634f
#define NL2E  (-0.72134752044448170f)   /* -0.5*log2(e) */
#define LN2   0.6931471805599453f
#define LN2PI 1.8378770664093453f
/* warm-up-only emission pre-scale 2^16 (round-2 lesson: store phase must
   stay at RAW emission scale to reproduce the reference's EPS saturation). */
#define EMSC  16.0f

typedef float v2f __attribute__((ext_vector_type(2)));
typedef __attribute__((ext_vector_type(4))) float f32x4;

/* ---- DPP wave64 sum: VALU-only ---- */
template <int CTRL>
__device__ __forceinline__ float dpp_add(float x) {
  int y = __builtin_amdgcn_update_dpp(0, __float_as_int(x), CTRL, 0xF, 0xF, true);
  return x + __int_as_float(y);
}
__device__ __forceinline__ float wave_sum64(float x) {
  x = dpp_add<0x111>(x);
  x = dpp_add<0x112>(x);
  x = dpp_add<0x114>(x);
  x = dpp_add<0x118>(x);
  x = dpp_add<0x142>(x);
  x = dpp_add<0x143>(x);
  return __int_as_float(__builtin_amdgcn_readlane(__float_as_int(x), 63));
}

#define PKFMA(a, b, c) __builtin_elementwise_fma(a, b, c)

/* emission: exp2(cc + sum_f x*(x*civ + cmiv)); coeffs pre-scaled by -0.5*log2e */
__device__ __forceinline__ float em_pk(const float4& xa, const float4& xb,
                                       const v2f civ2[4], const v2f cmiv2[4],
                                       float cc) {
  v2f x0 = {xa.x, xa.y}, x1 = {xa.z, xa.w};
  v2f x2 = {xb.x, xb.y}, x3 = {xb.z, xb.w};
  v2f a0 = {cc, 0.f}, a1 = {0.f, 0.f};
  a0 = PKFMA(x0, PKFMA(x0, civ2[0], cmiv2[0]), a0);
  a1 = PKFMA(x1, PKFMA(x1, civ2[1], cmiv2[1]), a1);
  a0 = PKFMA(x2, PKFMA(x2, civ2[2], cmiv2[2]), a0);
  a1 = PKFMA(x3, PKFMA(x3, civ2[3], cmiv2[3]), a1);
  v2f s = a0 + a1;
  return __builtin_amdgcn_exp2f(s.x + s.y);
}

/* 64x64 matvec: quarter-read + partial-sum exchange.
   Round-6 post-mortem: full LDS broadcast (16 x ds_read_b128 = 16 KB
   data-return per wave-step) saturates the per-CU DS pipe (VALUBusy fell
   68->41% while time stayed ~flat). This version reads only the lane's own
   16-state quarter (4 x b128 broadcast within each 16-lane group, 4 KB/step:
   4x traffic cut; groups 2-way bank-aliased = free) and computes FOUR
   16-length partials, one per row in {l, l^16, l^32, l^48} (Tq = quarter-g
   slices of those rows, 64 VGPR, same 32 pk_fma). Full sums come from the
   lane-exchange identity: needed partial P(l,q) lives in lane l^16D, reg
   X[D], D = g XOR q (lane-uniform reg index), so
     y[l] = X0[l] + X1[l^16] + X2[l^32] + X3[l^48]
   with exchanges = swizzle-xor16 + 2 bpermutes (baseline-proven primitives,
   b32: negligible traffic). In-wave DS write->read order needs no barrier
   (single wave -- validated rounds 4/6). */
#define MATVEC(VV, MOUT)                                                      \
  {                                                                           \
    vtab[lane] = (VV);                                                        \
    f32x4 q0_ = vq[0], q1_ = vq[1], q2_ = vq[2], q3_ = vq[3];                 \
    v2f q0l_ = {q0_.x, q0_.y}, q0h_ = {q0_.z, q0_.w};                         \
    v2f q1l_ = {q1_.x, q1_.y}, q1h_ = {q1_.z, q1_.w};                         \
    v2f q2l_ = {q2_.x, q2_.y}, q2h_ = {q2_.z, q2_.w};                         \
    v2f q3l_ = {q3_.x, q3_.y}, q3h_ = {q3_.z, q3_.w};                         \
    float X0_, X1_, X2_, X3_;                                                 \
    _Pragma("unroll")                                                         \
    for (int d_ = 0; d_ < 4; ++d_) {                                          \
      v2f aA_ = {0.f, 0.f}, aB_ = {0.f, 0.f};                                 \
      aA_ = PKFMA(q0l_, Tq[d_][0], aA_);                                      \
      aB_ = PKFMA(q0h_, Tq[d_][1], aB_);                                      \
      aA_ = PKFMA(q1l_, Tq[d_][2], aA_);                                      \
      aB_ = PKFMA(q1h_, Tq[d_][3], aB_);                                      \
      aA_ = PKFMA(q2l_, Tq[d_][4], aA_);                                      \
      aB_ = PKFMA(q2h_, Tq[d_][5], aB_);                                      \
      aA_ = PKFMA(q3l_, Tq[d_][6], aA_);                                      \
      aB_ = PKFMA(q3h_, Tq[d_][7], aB_);                                      \
      v2f s_ = aA_ + aB_;                                                     \
      float xs_ = s_.x + s_.y;                                                \
      if (d_ == 0) X0_ = xs_;                                                 \
      else if (d_ == 1) X1_ = xs_;                                            \
      else if (d_ == 2) X2_ = xs_;                                            \
      else X3_ = xs_;                                                         \
    }                                                                         \
    float e1_ = __int_as_float(                                               \
        __builtin_amdgcn_ds_swizzle(__float_as_int(X1_), 0x401F));            \
    float e2_ = __int_as_float(                                               \
        __builtin_amdgcn_ds_bpermute(a32, __float_as_int(X2_)));              \
    float e3_ = __int_as_float(                                               \
        __builtin_amdgcn_ds_bpermute(a48, __float_as_int(X3_)));              \
    MOUT = (X0_ + e1_) + (e2_ + e3_);                                         \
  }

extern "C" __global__ void __launch_bounds__(64, 2)
hdphmm_fb(const float* __restrict__ obs,
          const float* __restrict__ beta_logits,
          const float* __restrict__ pi_logits,
          const float* __restrict__ means,
          const float* __restrict__ log_vars,
          float* __restrict__ out) {
  const int lane = threadIdx.x;
  const int bid  = blockIdx.x;
  const int g16  = (lane >> 4) << 4;               /* 16*g: own quarter base */
  const int a32  = ((lane ^ 32) & 63) << 2;        /* bpermute addrs */
  const int a48  = ((lane ^ 48) & 63) << 2;

  __shared__ __align__(8) float2 sstat[K_N];
  __shared__ float sb[K_N];
  __shared__ __align__(16) float vtab[K_N];        /* state broadcast table */
  const f32x4* vq = reinterpret_cast<const f32x4*>(vtab) + (lane >> 4) * 4;

  float* alpha   = out;
  float* betaout = out + (size_t)T_N * K_N;

  /* ---- per-lane emission coefficients (lane == state), packed ---- */
  v2f civ2[4], cmiv2[4];
  float c0, cw;   /* c0: raw scale (store phase); cw: +2^16 (warm-up only) */
  {
    const float4* mp = reinterpret_cast<const float4*>(means + lane * F_N);
    const float4* lp = reinterpret_cast<const float4*>(log_vars + lane * F_N);
    float4 m0 = mp[0], m1 = mp[1];
    float4 l0 = lp[0], l1 = lp[1];
    float mu[8] = {m0.x, m0.y, m0.z, m0.w, m1.x, m1.y, m1.z, m1.w};
    float lv[8] = {l0.x, l0.y, l0.z, l0.w, l1.x, l1.y, l1.z, l1.w};
    float cst = F_N * LN2PI;
#pragma unroll
    for (int f = 0; f < 8; ++f) {
      float iv = __builtin_amdgcn_exp2f(-lv[f] * LOG2E);
      cst += lv[f] + mu[f] * mu[f] * iv;
      float cf  = NL2E * iv;
      civ2[f >> 1][f & 1]  = cf;
      cmiv2[f >> 1][f & 1] = -2.0f * mu[f] * cf;
    }
    c0 = NL2E * cst;
    cw = c0 + EMSC;
  }

  /* ---- softmax stats (max, 1/sum) of pi_logits row `lane` -> LDS ---- */
  {
    const float4* pr4 = reinterpret_cast<const float4*>(pi_logits + lane * K_N);
    float mx = -3.0e38f;
#pragma unroll
    for (int k = 0; k < 16; ++k) {
      float4 r = pr4[k];
      mx = fmaxf(mx, fmaxf(fmaxf(r.x, r.y), fmaxf(r.z, r.w)));
    }
    float s = 0.0f;
#pragma unroll
    for (int k = 0; k < 16; ++k) {
      float4 r = pr4[k];
      s += __builtin_amdgcn_exp2f((r.x - mx) * LOG2E);
      s += __builtin_amdgcn_exp2f((r.y - mx) * LOG2E);
      s += __builtin_amdgcn_exp2f((r.z - mx) * LOG2E);
      s += __builtin_amdgcn_exp2f((r.w - mx) * LOG2E);
    }
    sstat[lane] = make_float2(mx, __builtin_amdgcn_rcpf(s));
  }
  __syncthreads();

  /* ---- per-lane partial rows: Tq[D][c] = {M[l^16D][16g+2c], M[l^16D][16g+2c+1]} ---- */
  v2f Tq[4][8];

  if (bid < N_CH) {
    /* ================= FORWARD chunk =================
       y[c] = sum_k v[k]*trans[k][c]  =>  M = trans^T:
       M[r][k] = tn(k, r); stats indexed by k. Preamble-only scalar reads
       (pi_logits = 16 KB, L2-resident). */
#pragma unroll
    for (int d = 0; d < 4; ++d) {
      int row = lane ^ (16 * d);
#pragma unroll
      for (int c = 0; c < 8; ++c) {
        int k0 = g16 + 2 * c, k1 = k0 + 1;
        float2 s0 = sstat[k0], s1 = sstat[k1];
        float p0 = pi_logits[(size_t)k0 * K_N + row];
        float p1 = pi_logits[(size_t)k1 * K_N + row];
        Tq[d][c] = (v2f){__builtin_amdgcn_exp2f((p0 - s0.x) * LOG2E) * s0.y,
                         __builtin_amdgcn_exp2f((p1 - s1.x) * LOG2E) * s1.y};
      }
    }

    const int out_lo = bid * L_C;
    float v;
    int t_first;
    if (bid == 0) {
      /* exact stick-breaking init at RAW scale (reference EPS semantics) */
      float bl = beta_logits[lane];
      float ex = __builtin_amdgcn_exp2f(-bl * LOG2E);
      float bw = __builtin_amdgcn_rcpf(1.0f + ex);
      sb[lane] = 1.0f - bw;
      __syncthreads();
      float pr = 1.0f;
#pragma unroll
      for (int i = 0; i < 64; ++i) {
        float qv = sb[i];
        pr = (i < lane) ? pr * qv : pr;
      }
      float4 x0 = reinterpret_cast<const float4*>(obs)[0];
      float4 x1 = reinterpret_cast<const float4*>(obs)[1];
      v = bw * pr * em_pk(x0, x1, civ2, cmiv2, c0);
      t_first = 1;
    } else {
      const int t0 = out_lo - WARM;
      const float4* xp = reinterpret_cast<const float4*>(obs + t0 * F_N);
      v = em_pk(xp[0], xp[1], civ2, cmiv2, cw);   /* flat warm start, scaled */
      t_first = t0 + 1;
    }
    int obs_off = t_first * F_N;
    float4 xa, xb;
    {
      const float4* xp = reinterpret_cast<const float4*>(obs + obs_off);
      xa = xp[0]; xb = xp[1];
    }
    int out_off = out_lo * K_N + lane;

    /* ---- warm-up: scale-free recursion (scaled em), rescale every 8 ---- */
    const int wn8 = (bid == 0) ? 0 : (WARM >> 3);
#pragma unroll 1
    for (int o = 0; o < wn8; ++o) {
#pragma unroll
      for (int i = 0; i < 8; ++i) {
        float4 nxa = *reinterpret_cast<const float4*>(obs + obs_off + F_N);
        float4 nxb = *reinterpret_cast<const float4*>(obs + obs_off + F_N + 4);
        float m;
        MATVEC(v, m)
        float e = em_pk(xa, xb, civ2, cmiv2, cw);
        v = m * e;
        xa = nxa; xb = nxb; obs_off += F_N;
      }
      float Sw = wave_sum64(v);
      v *= __builtin_amdgcn_rcpf(Sw);
    }

    /* ---- store phase: RAW-scale em, reference EPS semantics ---- */
    float S = wave_sum64(v);
    float r_st = __builtin_amdgcn_rcpf(S + EPS_F);

#define FWD_SSTEP                                                             \
  {                                                                           \
    int offn = obs_off + F_N; offn = (offn > OBS_MAX) ? OBS_MAX : offn;       \
    float4 nxa = *reinterpret_cast<const float4*>(obs + offn);                \
    float4 nxb = *reinterpret_cast<const float4*>(obs + offn + 4);            \
    float m;                                                                  \
    MATVEC(v, m)                                                              \
    alpha[out_off] = v * r_st; out_off += K_N;                                \
    float e = em_pk(xa, xb, civ2, cmiv2, c0);                                 \
    float vn = m * (r_st * e);                                                \
    S = wave_sum64(vn);                                                       \
    r_st = __builtin_amdgcn_rcpf(S + EPS_F);                                  \
    v = vn; xa = nxa; xb = nxb; obs_off = offn;                               \
  }

#pragma unroll 2
    for (int it = 0; it < L_C - 1; ++it) FWD_SSTEP
#undef FWD_SSTEP
    alpha[out_off] = v * r_st;
    if (bid == N_CH - 1 && lane == 0) {
      float sl = S * r_st + EPS_F;
      out[(size_t)2 * T_N * K_N] = __builtin_amdgcn_logf(sl) * LN2;
    }
  } else {
    /* ================= BACKWARD chunk =================
       y[i] = sum_k trans[i][k]*w[k]  =>  M = trans:
       M[r][k] = tn(r, k); stats indexed by r. Coalesced float4 reads. */
#pragma unroll
    for (int d = 0; d < 4; ++d) {
      int row = lane ^ (16 * d);
      float2 st = sstat[row];
      const float4* rp =
          reinterpret_cast<const float4*>(pi_logits + (size_t)row * K_N + g16);
#pragma unroll
      for (int c4 = 0; c4 < 4; ++c4) {
        float4 r = rp[c4];
        Tq[d][2 * c4] =
            (v2f){__builtin_amdgcn_exp2f((r.x - st.x) * LOG2E) * st.y,
                  __builtin_amdgcn_exp2f((r.y - st.x) * LOG2E) * st.y};
        Tq[d][2 * c4 + 1] =
            (v2f){__builtin_amdgcn_exp2f((r.z - st.x) * LOG2E) * st.y,
                  __builtin_amdgcn_exp2f((r.w - st.x) * LOG2E) * st.y};
      }
    }

    const int cb   = bid - N_CH;
    const int t_lo = cb * L_C;
    const int t_hi = t_lo + L_C - 1;
    int t_top = t_hi + WARM;
    if (t_top > T_N - 1) t_top = T_N - 1;        /* clamp => exact bT anchor */
    const int s_top = (cb == N_CH - 1) ? T_N - 2 : t_hi;

    float w;
    {
      const float4* xp = reinterpret_cast<const float4*>(obs + t_top * F_N);
      w = em_pk(xp[0], xp[1], civ2, cmiv2, cw);   /* scale divided out later */
    }
    if (cb == N_CH - 1)
      betaout[(size_t)(T_N - 1) * K_N + lane] = 1.0f;
    int obs_off = (t_top - 1) * F_N;
    float4 xa, xb;
    {
      const float4* xp = reinterpret_cast<const float4*>(obs + obs_off);
      xa = xp[0]; xb = xp[1];
    }
    int out_off = s_top * K_N + lane;

    /* ---- warm-up (scale-free, scaled em), pw = warm_n - 1 steps ---- */
#define BWD_WSTEP                                                             \
  {                                                                           \
    float4 nxa = *reinterpret_cast<const float4*>(obs + obs_off - F_N);       \
    float4 nxb = *reinterpret_cast<const float4*>(obs + obs_off - F_N + 4);   \
    float m;                                                                  \
    MATVEC(w, m)                                                              \
    float e = em_pk(xa, xb, civ2, cmiv2, cw);                                 \
    w = m * e;                                                                \
    xa = nxa; xb = nxb; obs_off -= F_N;                                       \
  }

    const int pw  = (t_top - s_top) - 1;         /* 95 generic, 0 last chunk */
    const int pw8 = pw >> 3, pwr = pw & 7;
#pragma unroll 1
    for (int o = 0; o < pw8; ++o) {
#pragma unroll
      for (int i = 0; i < 8; ++i) BWD_WSTEP
      float Sw = wave_sum64(w);
      w *= __builtin_amdgcn_rcpf(Sw);
    }
#pragma unroll 1
    for (int it = 0; it < pwr; ++it) BWD_WSTEP
#undef BWD_WSTEP

    /* ---- transition: exact direction normalize, switch to RAW-scale em ---- */
    float u, S, r_st;
    {
      float m;
      MATVEC(w, m)
      float Sm = wave_sum64(m);
      u = m * __builtin_amdgcn_rcpf(Sm);          /* b(s_top), sum == 1 */
      float e = em_pk(xa, xb, civ2, cmiv2, c0);   /* em[s_top], raw scale */
      w = u * e;
      S = wave_sum64(u);
      r_st = __builtin_amdgcn_rcpf(S + EPS_F);
      int offn = obs_off - F_N; offn = (offn < 0) ? 0 : offn;
      xa = *reinterpret_cast<const float4*>(obs + offn);
      xb = *reinterpret_cast<const float4*>(obs + offn + 4);
      obs_off = offn;
    }

#define BWD_SSTEP                                                             \
  {                                                                           \
    int offn = obs_off - F_N; offn = (offn < 0) ? 0 : offn;                   \
    float4 nxa = *reinterpret_cast<const float4*>(obs + offn);                \
    float4 nxb = *reinterpret_cast<const float4*>(obs + offn + 4);            \
    float m;                                                                  \
    MATVEC(w, m)                                                              \
    betaout[out_off] = u * r_st; out_off -= K_N;                              \
    float u2 = m * r_st;                                                      \
    float e = em_pk(xa, xb, civ2, cmiv2, c0);                                 \
    w = u2 * e;                                                               \
    S = wave_sum64(u2);                                                       \
    r_st = __builtin_amdgcn_rcpf(S + EPS_F);                                  \
    u = u2; xa = nxa; xb = nxb; obs_off = offn;                               \
  }

    const int store_n = s_top - t_lo;
#pragma unroll 2
    for (int it = 0; it < store_n; ++it) BWD_SSTEP
#undef BWD_SSTEP
    betaout[t_lo * K_N + lane] = u * r_st;
  }
}

extern "C" void kernel_launch(void* const* d_in, const int* in_sizes, int n_in,
                              void* d_out, int out_size, void* d_ws, size_t ws_size,
                              hipStream_t stream) {
  (void)in_sizes; (void)n_in; (void)out_size; (void)d_ws; (void)ws_size;
  const float* obs  = (const float*)d_in[0];
  const float* bl   = (const float*)d_in[1];
  const float* pi   = (const float*)d_in[2];
  const float* mns  = (const float*)d_in[3];
  const float* lvs  = (const float*)d_in[4];
  hipLaunchKernelGGL(hdphmm_fb, dim3(2 * N_CH), dim3(64), 0, stream,
                     obs, bl, pi, mns, lvs, (float*)d_out);
}

// Round 8
// 149.748 us; speedup vs baseline: 1.5113x; 1.0980x over previous
//
#include <hip/hip_runtime.h>

#define T_N   131072
#define K_N   64
#define L_C   64
#define F_N   8
#define N_CH  (T_N / L_C)   /* 2048 chunks per direction */
#define WARM  32
#define EPS_F 1e-10f
#define OBS_MAX ((T_N - 1) * F_N)

#define LOG2E 1.4426950408889634f
#define NL2E  (-0.72134752044448170f)   /* -0.5*log2(e) */
#define LN2   0.6931471805599453f
#define LN2PI 1.8378770664093453f
/* warm-up-only emission pre-scale 2^16 (round-2 lesson: store phase must
   stay at RAW emission scale to reproduce the reference's EPS saturation).
   WARM=32 rationale (round-8): direction is scale-invariant (EPS changes
   stored scale only), and mixing for softmax(N(0,1)) rows is lambda2~0.125
   -> truncation ~1e-29 after 32 steps. Warm fraction drops 96/224 -> 32/96
   while L_C=64 doubles stream count (2 -> 4 waves/SIMD). */
#define EMSC  16.0f

typedef float v2f __attribute__((ext_vector_type(2)));
typedef __attribute__((ext_vector_type(4))) float f32x4;

/* ---- DPP wave64 sum: VALU-only ---- */
template <int CTRL>
__device__ __forceinline__ float dpp_add(float x) {
  int y = __builtin_amdgcn_update_dpp(0, __float_as_int(x), CTRL, 0xF, 0xF, true);
  return x + __int_as_float(y);
}
__device__ __forceinline__ float wave_sum64(float x) {
  x = dpp_add<0x111>(x);
  x = dpp_add<0x112>(x);
  x = dpp_add<0x114>(x);
  x = dpp_add<0x118>(x);
  x = dpp_add<0x142>(x);
  x = dpp_add<0x143>(x);
  return __int_as_float(__builtin_amdgcn_readlane(__float_as_int(x), 63));
}

#define PKFMA(a, b, c) __builtin_elementwise_fma(a, b, c)

/* emission: exp2(cc + sum_f x*(x*civ + cmiv)); coeffs pre-scaled by -0.5*log2e */
__device__ __forceinline__ float em_pk(const float4& xa, const float4& xb,
                                       const v2f civ2[4], const v2f cmiv2[4],
                                       float cc) {
  v2f x0 = {xa.x, xa.y}, x1 = {xa.z, xa.w};
  v2f x2 = {xb.x, xb.y}, x3 = {xb.z, xb.w};
  v2f a0 = {cc, 0.f}, a1 = {0.f, 0.f};
  a0 = PKFMA(x0, PKFMA(x0, civ2[0], cmiv2[0]), a0);
  a1 = PKFMA(x1, PKFMA(x1, civ2[1], cmiv2[1]), a1);
  a0 = PKFMA(x2, PKFMA(x2, civ2[2], cmiv2[2]), a0);
  a1 = PKFMA(x3, PKFMA(x3, civ2[3], cmiv2[3]), a1);
  v2f s = a0 + a1;
  return __builtin_amdgcn_exp2f(s.x + s.y);
}

/* 64x64 matvec: quarter-read + partial-sum exchange (round-7 structure).
   Lane reads its own 16-state quarter (4 x b128 broadcast, 4 KB/wave-step),
   computes FOUR 16-length partials for rows {l, l^16, l^32, l^48}
   (Tq = quarter-g slices, 64 VGPR, 32 pk_fma), and combines via
     y[l] = X0[l] + X1[l^16] + X2[l^32] + X3[l^48]
   (swizzle-xor16 + 2 bpermutes). In-wave DS write->read needs no barrier
   (single wave -- validated rounds 4/6/7). */
#define MATVEC(VV, MOUT)                                                      \
  {                                                                           \
    vtab[lane] = (VV);                                                        \
    f32x4 q0_ = vq[0], q1_ = vq[1], q2_ = vq[2], q3_ = vq[3];                 \
    v2f q0l_ = {q0_.x, q0_.y}, q0h_ = {q0_.z, q0_.w};                         \
    v2f q1l_ = {q1_.x, q1_.y}, q1h_ = {q1_.z, q1_.w};                         \
    v2f q2l_ = {q2_.x, q2_.y}, q2h_ = {q2_.z, q2_.w};                         \
    v2f q3l_ = {q3_.x, q3_.y}, q3h_ = {q3_.z, q3_.w};                         \
    float X0_, X1_, X2_, X3_;                                                 \
    _Pragma("unroll")                                                         \
    for (int d_ = 0; d_ < 4; ++d_) {                                          \
      v2f aA_ = {0.f, 0.f}, aB_ = {0.f, 0.f};                                 \
      aA_ = PKFMA(q0l_, Tq[d_][0], aA_);                                      \
      aB_ = PKFMA(q0h_, Tq[d_][1], aB_);                                      \
      aA_ = PKFMA(q1l_, Tq[d_][2], aA_);                                      \
      aB_ = PKFMA(q1h_, Tq[d_][3], aB_);                                      \
      aA_ = PKFMA(q2l_, Tq[d_][4], aA_);                                      \
      aB_ = PKFMA(q2h_, Tq[d_][5], aB_);                                      \
      aA_ = PKFMA(q3l_, Tq[d_][6], aA_);                                      \
      aB_ = PKFMA(q3h_, Tq[d_][7], aB_);                                      \
      v2f s_ = aA_ + aB_;                                                     \
      float xs_ = s_.x + s_.y;                                                \
      if (d_ == 0) X0_ = xs_;                                                 \
      else if (d_ == 1) X1_ = xs_;                                            \
      else if (d_ == 2) X2_ = xs_;                                            \
      else X3_ = xs_;                                                         \
    }                                                                         \
    float e1_ = __int_as_float(                                               \
        __builtin_amdgcn_ds_swizzle(__float_as_int(X1_), 0x401F));            \
    float e2_ = __int_as_float(                                               \
        __builtin_amdgcn_ds_bpermute(a32, __float_as_int(X2_)));              \
    float e3_ = __int_as_float(                                               \
        __builtin_amdgcn_ds_bpermute(a48, __float_as_int(X3_)));              \
    MOUT = (X0_ + e1_) + (e2_ + e3_);                                         \
  }

extern "C" __global__ void __launch_bounds__(64, 4)
hdphmm_fb(const float* __restrict__ obs,
          const float* __restrict__ beta_logits,
          const float* __restrict__ pi_logits,
          const float* __restrict__ means,
          const float* __restrict__ log_vars,
          float* __restrict__ out) {
  const int lane = threadIdx.x;
  const int bid  = blockIdx.x;
  const int g16  = (lane >> 4) << 4;               /* 16*g: own quarter base */
  const int a32  = ((lane ^ 32) & 63) << 2;        /* bpermute addrs */
  const int a48  = ((lane ^ 48) & 63) << 2;

  __shared__ __align__(8) float2 sstat[K_N];
  __shared__ float sb[K_N];
  __shared__ __align__(16) float vtab[K_N];        /* state broadcast table */
  const f32x4* vq = reinterpret_cast<const f32x4*>(vtab) + (lane >> 4) * 4;

  float* alpha   = out;
  float* betaout = out + (size_t)T_N * K_N;

  /* ---- per-lane emission coefficients (lane == state), packed ---- */
  v2f civ2[4], cmiv2[4];
  float c0, cw;   /* c0: raw scale (store phase); cw: +2^16 (warm-up only) */
  {
    const float4* mp = reinterpret_cast<const float4*>(means + lane * F_N);
    const float4* lp = reinterpret_cast<const float4*>(log_vars + lane * F_N);
    float4 m0 = mp[0], m1 = mp[1];
    float4 l0 = lp[0], l1 = lp[1];
    float mu[8] = {m0.x, m0.y, m0.z, m0.w, m1.x, m1.y, m1.z, m1.w};
    float lv[8] = {l0.x, l0.y, l0.z, l0.w, l1.x, l1.y, l1.z, l1.w};
    float cst = F_N * LN2PI;
#pragma unroll
    for (int f = 0; f < 8; ++f) {
      float iv = __builtin_amdgcn_exp2f(-lv[f] * LOG2E);
      cst += lv[f] + mu[f] * mu[f] * iv;
      float cf  = NL2E * iv;
      civ2[f >> 1][f & 1]  = cf;
      cmiv2[f >> 1][f & 1] = -2.0f * mu[f] * cf;
    }
    c0 = NL2E * cst;
    cw = c0 + EMSC;
  }

  /* ---- softmax stats (max, 1/sum) of pi_logits row `lane` -> LDS ---- */
  {
    const float4* pr4 = reinterpret_cast<const float4*>(pi_logits + lane * K_N);
    float mx = -3.0e38f;
#pragma unroll
    for (int k = 0; k < 16; ++k) {
      float4 r = pr4[k];
      mx = fmaxf(mx, fmaxf(fmaxf(r.x, r.y), fmaxf(r.z, r.w)));
    }
    float s = 0.0f;
#pragma unroll
    for (int k = 0; k < 16; ++k) {
      float4 r = pr4[k];
      s += __builtin_amdgcn_exp2f((r.x - mx) * LOG2E);
      s += __builtin_amdgcn_exp2f((r.y - mx) * LOG2E);
      s += __builtin_amdgcn_exp2f((r.z - mx) * LOG2E);
      s += __builtin_amdgcn_exp2f((r.w - mx) * LOG2E);
    }
    sstat[lane] = make_float2(mx, __builtin_amdgcn_rcpf(s));
  }
  __syncthreads();

  /* ---- per-lane partial rows: Tq[D][c] = {M[l^16D][16g+2c], M[l^16D][16g+2c+1]} ---- */
  v2f Tq[4][8];

  if (bid < N_CH) {
    /* ================= FORWARD chunk =================
       y[c] = sum_k v[k]*trans[k][c]  =>  M = trans^T:
       M[r][k] = tn(k, r); stats indexed by k. Preamble-only scalar reads
       (pi_logits = 16 KB, L2-resident). */
#pragma unroll
    for (int d = 0; d < 4; ++d) {
      int row = lane ^ (16 * d);
#pragma unroll
      for (int c = 0; c < 8; ++c) {
        int k0 = g16 + 2 * c, k1 = k0 + 1;
        float2 s0 = sstat[k0], s1 = sstat[k1];
        float p0 = pi_logits[(size_t)k0 * K_N + row];
        float p1 = pi_logits[(size_t)k1 * K_N + row];
        Tq[d][c] = (v2f){__builtin_amdgcn_exp2f((p0 - s0.x) * LOG2E) * s0.y,
                         __builtin_amdgcn_exp2f((p1 - s1.x) * LOG2E) * s1.y};
      }
    }

    const int out_lo = bid * L_C;
    float v;
    int t_first;
    if (bid == 0) {
      /* exact stick-breaking init at RAW scale (reference EPS semantics) */
      float bl = beta_logits[lane];
      float ex = __builtin_amdgcn_exp2f(-bl * LOG2E);
      float bw = __builtin_amdgcn_rcpf(1.0f + ex);
      sb[lane] = 1.0f - bw;
      __syncthreads();
      float pr = 1.0f;
#pragma unroll
      for (int i = 0; i < 64; ++i) {
        float qv = sb[i];
        pr = (i < lane) ? pr * qv : pr;
      }
      float4 x0 = reinterpret_cast<const float4*>(obs)[0];
      float4 x1 = reinterpret_cast<const float4*>(obs)[1];
      v = bw * pr * em_pk(x0, x1, civ2, cmiv2, c0);
      t_first = 1;
    } else {
      const int t0 = out_lo - WARM;
      const float4* xp = reinterpret_cast<const float4*>(obs + t0 * F_N);
      v = em_pk(xp[0], xp[1], civ2, cmiv2, cw);   /* flat warm start, scaled */
      t_first = t0 + 1;
    }
    int obs_off = t_first * F_N;
    float4 xa, xb;
    {
      const float4* xp = reinterpret_cast<const float4*>(obs + obs_off);
      xa = xp[0]; xb = xp[1];
    }
    int out_off = out_lo * K_N + lane;

    /* ---- warm-up: scale-free recursion (scaled em), rescale every 8 ---- */
    const int wn8 = (bid == 0) ? 0 : (WARM >> 3);
#pragma unroll 1
    for (int o = 0; o < wn8; ++o) {
#pragma unroll
      for (int i = 0; i < 8; ++i) {
        float4 nxa = *reinterpret_cast<const float4*>(obs + obs_off + F_N);
        float4 nxb = *reinterpret_cast<const float4*>(obs + obs_off + F_N + 4);
        float m;
        MATVEC(v, m)
        float e = em_pk(xa, xb, civ2, cmiv2, cw);
        v = m * e;
        xa = nxa; xb = nxb; obs_off += F_N;
      }
      float Sw = wave_sum64(v);
      v *= __builtin_amdgcn_rcpf(Sw);
    }

    /* ---- store phase: RAW-scale em, reference EPS semantics ---- */
    float S = wave_sum64(v);
    float r_st = __builtin_amdgcn_rcpf(S + EPS_F);

#define FWD_SSTEP                                                             \
  {                                                                           \
    int offn = obs_off + F_N; offn = (offn > OBS_MAX) ? OBS_MAX : offn;       \
    float4 nxa = *reinterpret_cast<const float4*>(obs + offn);                \
    float4 nxb = *reinterpret_cast<const float4*>(obs + offn + 4);            \
    float m;                                                                  \
    MATVEC(v, m)                                                              \
    alpha[out_off] = v * r_st; out_off += K_N;                                \
    float e = em_pk(xa, xb, civ2, cmiv2, c0);                                 \
    float vn = m * (r_st * e);                                                \
    S = wave_sum64(vn);                                                       \
    r_st = __builtin_amdgcn_rcpf(S + EPS_F);                                  \
    v = vn; xa = nxa; xb = nxb; obs_off = offn;                               \
  }

#pragma unroll 2
    for (int it = 0; it < L_C - 1; ++it) FWD_SSTEP
#undef FWD_SSTEP
    alpha[out_off] = v * r_st;
    if (bid == N_CH - 1 && lane == 0) {
      float sl = S * r_st + EPS_F;
      out[(size_t)2 * T_N * K_N] = __builtin_amdgcn_logf(sl) * LN2;
    }
  } else {
    /* ================= BACKWARD chunk =================
       y[i] = sum_k trans[i][k]*w[k]  =>  M = trans:
       M[r][k] = tn(r, k); stats indexed by r. Coalesced float4 reads. */
#pragma unroll
    for (int d = 0; d < 4; ++d) {
      int row = lane ^ (16 * d);
      float2 st = sstat[row];
      const float4* rp =
          reinterpret_cast<const float4*>(pi_logits + (size_t)row * K_N + g16);
#pragma unroll
      for (int c4 = 0; c4 < 4; ++c4) {
        float4 r = rp[c4];
        Tq[d][2 * c4] =
            (v2f){__builtin_amdgcn_exp2f((r.x - st.x) * LOG2E) * st.y,
                  __builtin_amdgcn_exp2f((r.y - st.x) * LOG2E) * st.y};
        Tq[d][2 * c4 + 1] =
            (v2f){__builtin_amdgcn_exp2f((r.z - st.x) * LOG2E) * st.y,
                  __builtin_amdgcn_exp2f((r.w - st.x) * LOG2E) * st.y};
      }
    }

    const int cb   = bid - N_CH;
    const int t_lo = cb * L_C;
    const int t_hi = t_lo + L_C - 1;
    int t_top = t_hi + WARM;
    if (t_top > T_N - 1) t_top = T_N - 1;        /* clamp => exact bT anchor */
    const int s_top = (cb == N_CH - 1) ? T_N - 2 : t_hi;

    float w;
    {
      const float4* xp = reinterpret_cast<const float4*>(obs + t_top * F_N);
      w = em_pk(xp[0], xp[1], civ2, cmiv2, cw);   /* scale divided out later */
    }
    if (cb == N_CH - 1)
      betaout[(size_t)(T_N - 1) * K_N + lane] = 1.0f;
    int obs_off = (t_top - 1) * F_N;
    float4 xa, xb;
    {
      const float4* xp = reinterpret_cast<const float4*>(obs + obs_off);
      xa = xp[0]; xb = xp[1];
    }
    int out_off = s_top * K_N + lane;

    /* ---- warm-up (scale-free, scaled em), pw = warm_n - 1 steps ---- */
#define BWD_WSTEP                                                             \
  {                                                                           \
    float4 nxa = *reinterpret_cast<const float4*>(obs + obs_off - F_N);       \
    float4 nxb = *reinterpret_cast<const float4*>(obs + obs_off - F_N + 4);   \
    float m;                                                                  \
    MATVEC(w, m)                                                              \
    float e = em_pk(xa, xb, civ2, cmiv2, cw);                                 \
    w = m * e;                                                                \
    xa = nxa; xb = nxb; obs_off -= F_N;                                       \
  }

    const int pw  = (t_top - s_top) - 1;         /* 31 generic, 0 last chunk */
    const int pw8 = pw >> 3, pwr = pw & 7;
#pragma unroll 1
    for (int o = 0; o < pw8; ++o) {
#pragma unroll
      for (int i = 0; i < 8; ++i) BWD_WSTEP
      float Sw = wave_sum64(w);
      w *= __builtin_amdgcn_rcpf(Sw);
    }
#pragma unroll 1
    for (int it = 0; it < pwr; ++it) BWD_WSTEP
#undef BWD_WSTEP

    /* ---- transition: exact direction normalize, switch to RAW-scale em ---- */
    float u, S, r_st;
    {
      float m;
      MATVEC(w, m)
      float Sm = wave_sum64(m);
      u = m * __builtin_amdgcn_rcpf(Sm);          /* b(s_top), sum == 1 */
      float e = em_pk(xa, xb, civ2, cmiv2, c0);   /* em[s_top], raw scale */
      w = u * e;
      S = wave_sum64(u);
      r_st = __builtin_amdgcn_rcpf(S + EPS_F);
      int offn = obs_off - F_N; offn = (offn < 0) ? 0 : offn;
      xa = *reinterpret_cast<const float4*>(obs + offn);
      xb = *reinterpret_cast<const float4*>(obs + offn + 4);
      obs_off = offn;
    }

#define BWD_SSTEP                                                             \
  {                                                                           \
    int offn = obs_off - F_N; offn = (offn < 0) ? 0 : offn;                   \
    float4 nxa = *reinterpret_cast<const float4*>(obs + offn);                \
    float4 nxb = *reinterpret_cast<const float4*>(obs + offn + 4);            \
    float m;                                                                  \
    MATVEC(w, m)                                                              \
    betaout[out_off] = u * r_st; out_off -= K_N;                              \
    float u2 = m * r_st;                                                      \
    float e = em_pk(xa, xb, civ2, cmiv2, c0);                                 \
    w = u2 * e;                                                               \
    S = wave_sum64(u2);                                                       \
    r_st = __builtin_amdgcn_rcpf(S + EPS_F);                                  \
    u = u2; xa = nxa; xb = nxb; obs_off = offn;                               \
  }

    const int store_n = s_top - t_lo;
#pragma unroll 2
    for (int it = 0; it < store_n; ++it) BWD_SSTEP
#undef BWD_SSTEP
    betaout[t_lo * K_N + lane] = u * r_st;
  }
}

extern "C" void kernel_launch(void* const* d_in, const int* in_sizes, int n_in,
                              void* d_out, int out_size, void* d_ws, size_t ws_size,
                              hipStream_t stream) {
  (void)in_sizes; (void)n_in; (void)out_size; (void)d_ws; (void)ws_size;
  const float* obs  = (const float*)d_in[0];
  const float* bl   = (const float*)d_in[1];
  const float* pi   = (const float*)d_in[2];
  const float* mns  = (const float*)d_in[3];
  const float* lvs  = (const float*)d_in[4];
  hipLaunchKernelGGL(hdphmm_fb, dim3(2 * N_CH), dim3(64), 0, stream,
                     obs, bl, pi, mns, lvs, (float*)d_out);
}